// Round 3
// baseline (260.108 us; speedup 1.0000x reference)
//
#include <hip/hip_runtime.h>
#include <hip/hip_bf16.h>

#define B_     32
#define C_     256
#define T_     4096
#define NH_    8
#define DH_    64

__global__ __launch_bounds__(256) void k_prep(
    const float* __restrict__ query, const float* __restrict__ Wkv,
    const float* __restrict__ bkv, const float* __restrict__ Wq,
    const float* __restrict__ bq, float* __restrict__ qWt,
    float* __restrict__ qb) {
  const int n = blockIdx.x;
  const int b = blockIdx.y;
  const int t = threadIdx.x;
  __shared__ float qrow_s[C_];
  __shared__ float psum[4 * 64];
  __shared__ float qsh[64];
  __shared__ float pb_s[64];

  qrow_s[t] = query[(size_t)b * C_ + t];
  __syncthreads();

  {
    const int d = t & 63, ch = t >> 6;
    const float* wrow = Wq + (size_t)(n * DH_ + d) * C_ + ch * 64;
    const float* qr = qrow_s + ch * 64;
    float s = 0.f;
    #pragma unroll
    for (int c = 0; c < 64; c += 4) {
      float4 w = *(const float4*)(wrow + c);
      s += w.x * qr[c] + w.y * qr[c + 1] + w.z * qr[c + 2] + w.w * qr[c + 3];
    }
    psum[ch * 64 + d] = s;
  }
  __syncthreads();
  if (t < 64)
    qsh[t] = bq[n * DH_ + t] + psum[t] + psum[64 + t] + psum[128 + t] + psum[192 + t];
  __syncthreads();

  const float scale = 0.125f;
  {
    const float* wk = Wkv + (size_t)(n * DH_) * C_ + t;
    float acc = 0.f;
    #pragma unroll 8
    for (int dd = 0; dd < DH_; ++dd) acc += qsh[dd] * wk[(size_t)dd * C_];
    qWt[((size_t)b * C_ + t) * NH_ + n] = acc * scale;
  }
  if (t < 64) pb_s[t] = qsh[t] * bkv[n * DH_ + t];
  __syncthreads();
  if (t == 0) {
    float s = 0.f;
    #pragma unroll 8
    for (int dd = 0; dd < 64; ++dd) s += pb_s[dd];
    qb[b * NH_ + n] = s * scale;
  }
}

// Full-channel logits per block: grid (8 jt, B_) x 512 threads.
__global__ __launch_bounds__(512) void k_logits(
    const float* __restrict__ x, const float* __restrict__ qWt,
    const float* __restrict__ qbv, float* __restrict__ lgraw,
    float* __restrict__ stats) {
  const int jt = blockIdx.x;
  const int b  = blockIdx.y;
  const int t  = threadIdx.x;
  const int tj = t & 255;
  const int th = t >> 8;
  __shared__ float qws[C_ * NH_];     // 8 KB
  __shared__ float red[256 * 16];     // 16 KB half-1 partials
  __shared__ float sred[8][4];
  __shared__ float ssum[8][4];
  __shared__ float Msh[8];

  {
    const float4 v = *(const float4*)(qWt + (size_t)b * (C_ * NH_) + t * 4);
    *(float4*)(qws + t * 4) = v;
  }
  __syncthreads();

  const int j = jt * 512 + tj * 2;
  const float* xb = x + ((size_t)b * C_ + th * 128) * T_ + j;
  const float* qb = qbv + b * NH_;

  float acc0[NH_], acc1[NH_];
  #pragma unroll
  for (int n = 0; n < NH_; ++n) {
    const float init = (th == 0) ? qb[n] : 0.f;
    acc0[n] = init; acc1[n] = init;
  }

  for (int c0 = 0; c0 < 128; c0 += 16) {
    float2 xv[16];
    #pragma unroll
    for (int cc = 0; cc < 16; ++cc)
      xv[cc] = *(const float2*)(xb + (size_t)(c0 + cc) * T_);
    #pragma unroll
    for (int cc = 0; cc < 16; ++cc) {
      const float4 w0 = *(const float4*)(qws + (th * 128 + c0 + cc) * 8);
      const float4 w1 = *(const float4*)(qws + (th * 128 + c0 + cc) * 8 + 4);
      acc0[0] += w0.x * xv[cc].x; acc1[0] += w0.x * xv[cc].y;
      acc0[1] += w0.y * xv[cc].x; acc1[1] += w0.y * xv[cc].y;
      acc0[2] += w0.z * xv[cc].x; acc1[2] += w0.z * xv[cc].y;
      acc0[3] += w0.w * xv[cc].x; acc1[3] += w0.w * xv[cc].y;
      acc0[4] += w1.x * xv[cc].x; acc1[4] += w1.x * xv[cc].y;
      acc0[5] += w1.y * xv[cc].x; acc1[5] += w1.y * xv[cc].y;
      acc0[6] += w1.z * xv[cc].x; acc1[6] += w1.z * xv[cc].y;
      acc0[7] += w1.w * xv[cc].x; acc1[7] += w1.w * xv[cc].y;
    }
  }

  if (th == 1) {
    float* r = red + tj * 16;
    #pragma unroll
    for (int n = 0; n < NH_; ++n) { r[n] = acc0[n]; r[8 + n] = acc1[n]; }
  }
  __syncthreads();
  if (th == 0) {
    const float* r = red + tj * 16;
    #pragma unroll
    for (int n = 0; n < NH_; ++n) { acc0[n] += r[n]; acc1[n] += r[8 + n]; }
    float* lg = lgraw + ((size_t)b * NH_) * T_ + j;
    #pragma unroll
    for (int n = 0; n < NH_; ++n) {
      float2 o; o.x = acc0[n]; o.y = acc1[n];
      *(float2*)(lg + (size_t)n * T_) = o;
    }
  }

  #pragma unroll
  for (int n = 0; n < NH_; ++n) {
    float mv = fmaxf(acc0[n], acc1[n]);
    #pragma unroll
    for (int o = 32; o >= 1; o >>= 1) mv = fmaxf(mv, __shfl_xor(mv, o));
    if (th == 0 && (tj & 63) == 0) sred[n][tj >> 6] = mv;
  }
  __syncthreads();
  if (t < 8)
    Msh[t] = fmaxf(fmaxf(sred[t][0], sred[t][1]), fmaxf(sred[t][2], sred[t][3]));
  __syncthreads();
  #pragma unroll
  for (int n = 0; n < NH_; ++n) {
    float sv = (th == 0) ? (expf(acc0[n] - Msh[n]) + expf(acc1[n] - Msh[n])) : 0.f;
    #pragma unroll
    for (int o = 32; o >= 1; o >>= 1) sv += __shfl_xor(sv, o);
    if (th == 0 && (tj & 63) == 0) ssum[n][tj >> 6] = sv;
  }
  __syncthreads();
  if (t < 8) {
    const float S = ssum[t][0] + ssum[t][1] + ssum[t][2] + ssum[t][3];
    float2 o; o.x = Msh[t]; o.y = S;
    *(float2*)(stats + ((size_t)(b * NH_ + t) * 8 + jt) * 2) = o;
  }
}

// xattn v2: LDS-issue fix. Thread (jh = t>>7, cp = t&127) owns channels
// {cp, cp+128} and j-half jh (16 of 32 per subtile).
// a_lds packed [jj][n] -> 2 broadcast b128 per jj fetch all 8 head weights;
// xs read as float4 over jj (1 b128 / 4 jj / channel). Pitch 36 keeps
// 16B alignment; start banks (4cp+jj)%32 are dense-optimal for b128.
#define BJ_  128
#define BJS_ 32
#define XP_  36
__global__ __launch_bounds__(256) void k_xattn(
    const float* __restrict__ x, const float* __restrict__ lgraw,
    const float* __restrict__ stats, float* __restrict__ part) {
  const int jt = blockIdx.x;
  const int b  = blockIdx.y;
  const int j0 = jt * BJ_;
  const int t  = threadIdx.x;
  __shared__ __align__(16) float xs[C_ * XP_];     // 36 KB
  __shared__ __align__(16) float a_lds[BJS_][8];   // 1 KB, [jj][n]
  __shared__ float Msh[NH_];
  __shared__ float Sish[NH_];

  if (t < NH_) {
    const float* st = stats + (size_t)(b * NH_ + t) * 8 * 2;
    float M = -3.4e38f;
    #pragma unroll
    for (int k = 0; k < 8; ++k) M = fmaxf(M, st[k * 2]);
    float S = 0.f;
    #pragma unroll
    for (int k = 0; k < 8; ++k) S += st[k * 2 + 1] * expf(st[k * 2] - M);
    Msh[t] = M; Sish[t] = 1.0f / S;
  }

  const float* xb  = x + (size_t)b * C_ * T_;
  const float* lgb = lgraw + (size_t)b * NH_ * T_ + j0;

  float acc0[NH_], acc1[NH_];
  #pragma unroll
  for (int n = 0; n < NH_; ++n) { acc0[n] = 0.f; acc1[n] = 0.f; }

  const int cr = t >> 3;          // staging row 0..31
  const int jc = (t & 7) * 4;     // staging j offset
  const int an = t >> 5;          // weight head 0..7
  const int aj = t & 31;          // weight j 0..31
  const int jh = t >> 7;          // j-half 0..1
  const int cp = t & 127;         // channel pair base
  const int c0i = cp, c1i = cp + 128;

  for (int sIt = 0; sIt < BJ_ / BJS_; ++sIt) {
    const int js = sIt * BJS_;
    __syncthreads();   // first iter also orders Msh/Sish
    #pragma unroll
    for (int p = 0; p < 8; ++p) {
      const int c = cr + p * 32;
      float4 vv = *(const float4*)(xb + (size_t)c * T_ + j0 + js + jc);
      *(float4*)&xs[c * XP_ + jc] = vv;
    }
    {
      const float lv = lgb[(size_t)an * T_ + js + aj];
      a_lds[aj][an] = expf(lv - Msh[an]) * Sish[an];
    }
    __syncthreads();
    #pragma unroll
    for (int g = 0; g < 4; ++g) {
      const int jj4 = jh * 16 + g * 4;
      const float4 xv0 = *(const float4*)&xs[c0i * XP_ + jj4];
      const float4 xv1 = *(const float4*)&xs[c1i * XP_ + jj4];
      #pragma unroll
      for (int q = 0; q < 4; ++q) {
        const float4 wlo = *(const float4*)&a_lds[jj4 + q][0];
        const float4 whi = *(const float4*)&a_lds[jj4 + q][4];
        const float xa = (q == 0) ? xv0.x : (q == 1) ? xv0.y : (q == 2) ? xv0.z : xv0.w;
        const float xc = (q == 0) ? xv1.x : (q == 1) ? xv1.y : (q == 2) ? xv1.z : xv1.w;
        acc0[0] += wlo.x * xa; acc1[0] += wlo.x * xc;
        acc0[1] += wlo.y * xa; acc1[1] += wlo.y * xc;
        acc0[2] += wlo.z * xa; acc1[2] += wlo.z * xc;
        acc0[3] += wlo.w * xa; acc1[3] += wlo.w * xc;
        acc0[4] += whi.x * xa; acc1[4] += whi.x * xc;
        acc0[5] += whi.y * xa; acc1[5] += whi.y * xc;
        acc0[6] += whi.z * xa; acc1[6] += whi.z * xc;
        acc0[7] += whi.w * xa; acc1[7] += whi.w * xc;
      }
    }
  }

  // merge jh halves via LDS (xs reused; once per block, conflicts negligible)
  __syncthreads();
  if (jh == 1) {
    float* r = &xs[cp * 16];
    *(float4*)&r[0]  = make_float4(acc0[0], acc0[1], acc0[2], acc0[3]);
    *(float4*)&r[4]  = make_float4(acc0[4], acc0[5], acc0[6], acc0[7]);
    *(float4*)&r[8]  = make_float4(acc1[0], acc1[1], acc1[2], acc1[3]);
    *(float4*)&r[12] = make_float4(acc1[4], acc1[5], acc1[6], acc1[7]);
  }
  __syncthreads();
  if (jh == 0) {
    const float* r = &xs[cp * 16];
    float* pb = part + ((size_t)b * 32 + jt) * (NH_ * C_);
    #pragma unroll
    for (int n = 0; n < NH_; ++n) {
      pb[n * C_ + c0i] = acc0[n] + r[n];
      pb[n * C_ + c1i] = acc1[n] + r[8 + n];
    }
  }
}

// Reduce part + v-projection: grid (NH_, B_) x 256.
__global__ __launch_bounds__(256) void k_out2(
    const float* __restrict__ part, const float* __restrict__ Wkv,
    const float* __restrict__ bkv, float* __restrict__ outvG) {
  const int n = blockIdx.x;
  const int b = blockIdx.y;
  const int t = threadIdx.x;
  __shared__ float xa[C_];
  __shared__ float psum[4][64];

  {
    const float* pb = part + (size_t)b * 32 * (NH_ * C_) + n * C_ + t;
    float s = 0.f;
    #pragma unroll
    for (int jt = 0; jt < 32; ++jt) s += pb[(size_t)jt * (NH_ * C_)];
    xa[t] = s;
  }
  __syncthreads();

  {
    const int d = t & 63, q = t >> 6;
    const float* wrow = Wkv + (size_t)(512 + n * 64 + d) * C_ + q * 64;
    const float* xq = xa + q * 64;
    float s = 0.f;
    #pragma unroll
    for (int c = 0; c < 64; c += 4) {
      float4 w = *(const float4*)(wrow + c);
      s += w.x * xq[c] + w.y * xq[c + 1] + w.z * xq[c + 2] + w.w * xq[c + 3];
    }
    psum[q][d] = s;
  }
  __syncthreads();
  if (t < 64)
    outvG[(size_t)b * 512 + n * 64 + t] =
        bkv[512 + n * 64 + t] + psum[0][t] + psum[1][t] + psum[2][t] + psum[3][t];
}

__global__ __launch_bounds__(256) void k_fc(
    const float* __restrict__ outvG, const float* __restrict__ Wfc,
    const float* __restrict__ bfc, float* __restrict__ out) {
  __shared__ float ov[512];
  const int b = blockIdx.x;
  const int t = threadIdx.x;
  ov[t] = outvG[(size_t)b * 512 + t];
  ov[256 + t] = outvG[(size_t)b * 512 + 256 + t];
  __syncthreads();

  const float* wrow = Wfc + (size_t)t * 512;
  float s = bfc[t];
  #pragma unroll 8
  for (int o = 0; o < 512; o += 4) {
    float4 w = *(const float4*)(wrow + o);
    s += w.x * ov[o] + w.y * ov[o + 1] + w.z * ov[o + 2] + w.w * ov[o + 3];
  }
  out[(size_t)b * 256 + t] = fmaxf(s, 0.f);
}

extern "C" void kernel_launch(void* const* d_in, const int* in_sizes, int n_in,
                              void* d_out, int out_size, void* d_ws, size_t ws_size,
                              hipStream_t stream) {
  const float* x     = (const float*)d_in[0];
  const float* query = (const float*)d_in[1];
  const float* Wkv   = (const float*)d_in[2];
  const float* bkv   = (const float*)d_in[3];
  const float* Wq    = (const float*)d_in[4];
  const float* bq    = (const float*)d_in[5];
  const float* Wfc   = (const float*)d_in[6];
  const float* bfc   = (const float*)d_in[7];
  float* out = (float*)d_out;
  float* ws  = (float*)d_ws;

  float* qWt   = ws;                   // 65536 floats
  float* qb    = ws + 65536;           // 256 (pad 512)
  float* stats = ws + 66048;           // 32*8*8*2 = 4096
  float* lgraw = ws + 70144;           // 32*8*4096 = 1048576
  float* part  = ws + 1118720;         // 32*32*8*256 = 2097152
  float* outvG = ws + 3215872;         // 16384

  k_prep   <<<dim3(NH_, B_), 256, 0, stream>>>(query, Wkv, bkv, Wq, bq, qWt, qb);
  k_logits <<<dim3(8, B_),   512, 0, stream>>>(x, qWt, qb, lgraw, stats);
  k_xattn  <<<dim3(32, B_),  256, 0, stream>>>(x, lgraw, stats, part);
  k_out2   <<<dim3(NH_, B_), 256, 0, stream>>>(part, Wkv, bkv, outvG);
  k_fc     <<<B_,            256, 0, stream>>>(outvG, Wfc, bfc, out);
}